// Round 5
// baseline (132.270 us; speedup 1.0000x reference)
//
#include <hip/hip_runtime.h>
#include <math.h>

#define NQ 10
#define RPB 4            // rows per block
// Term table: 2048 slots, slot u: lane = u%256, s = u/256 (8 slots per lane).
// Lane groups (pow2-aligned for shfl_xor segment reduce):
//   lanes   0- 31: q8   lanes  32- 63: q9   lanes  64- 95: q0
//   lanes  96-127: q1   lanes 128-159: q6   lanes 160-191: q7
//   lanes 192-199: q4   lanes 200-207: q5   lanes 208-215: q2
//   lanes 216-223: q3   lanes 224-255: unused (coef 0)
// Valid term counts per q: 81,81,9,9,27,27,81,81,243,243 (total 882).

__device__ __forceinline__ void write_term(int u, const float abc[NQ][3],
                                           uint2* __restrict__ terms) {
    const int lane = u & 255, s = u >> 8;
    int q = -1, g0 = 0;
    if      (lane < 32)  { q = 8; g0 = 0;   }
    else if (lane < 64)  { q = 9; g0 = 32;  }
    else if (lane < 96)  { q = 0; g0 = 64;  }
    else if (lane < 128) { q = 1; g0 = 96;  }
    else if (lane < 160) { q = 6; g0 = 128; }
    else if (lane < 192) { q = 7; g0 = 160; }
    else if (lane < 200) { q = 4; g0 = 192; }
    else if (lane < 208) { q = 5; g0 = 200; }
    else if (lane < 216) { q = 2; g0 = 208; }
    else if (lane < 224) { q = 3; g0 = 216; }
    if (q < 0) { terms[u] = make_uint2(0u, 0u); return; }
    const int tau = (lane - g0) * 8 + s;

    // ring-2 Z-string for q (pure toggles)
    int m = 1 << q;
    for (int ii = NQ - 1; ii >= 0; --ii) {
        int tt = (ii + 2) % NQ;
        if ((m >> tt) & 1) m ^= 1 << ii;
    }
    const int Lp = __popc(m);
    int cnt = 1;
    for (int k = 0; k < Lp; ++k) cnt *= 3;
    if (tau >= cnt) { terms[u] = make_uint2(0u, 0u); return; }

    // expand: digit 0->X, 1->Y, 2->Z on each site of the Z-string
    int rem = tau;
    unsigned xm = 0, zm = 0;
    float coef = 1.f;
    for (int i = 0; i < NQ; ++i) {
        if ((m >> i) & 1) {
            int d = rem % 3; rem /= 3;
            coef *= abc[i][d];
            if (d == 0)      { xm |= 1u << i; }
            else if (d == 1) { xm |= 1u << i; zm |= 1u << i; }
            else             { zm |= 1u << i; }
        }
    }
    // ring-1 conjugation (CNOT(i,(i+1)%10), conjugate by i=9 first)
    unsigned sgn = 0;
    for (int i = NQ - 1; i >= 0; --i) {
        int c = i, tt = (i + 1) % NQ;
        unsigned xc = (xm >> c) & 1u, zt = (zm >> tt) & 1u;
        unsigned xt = (xm >> tt) & 1u, zc = (zm >> c) & 1u;
        sgn ^= xc & zt & (xt ^ zc ^ 1u);
        xm ^= xc << tt;
        zm ^= zt << c;
    }
    if (sgn) coef = -coef;

    unsigned nib = 0;
    for (int p = 0; p < 5; ++p) {
        unsigned c0 = ((xm >> (2 * p)) & 1u) | (((zm >> (2 * p)) & 1u) << 1);
        unsigned c1 = ((xm >> (2 * p + 1)) & 1u) | (((zm >> (2 * p + 1)) & 1u) << 1);
        nib |= (c0 | (c1 << 2)) << (4 * p);
    }
    terms[u] = make_uint2(nib, __float_as_uint(coef));
}

__global__ __launch_bounds__(1024) void qse_setup(const float* __restrict__ qw,
                                                  uint2* __restrict__ terms,
                                                  float* __restrict__ Rmat) {
    __shared__ float abc[NQ][3];
    const int t = threadIdx.x;
    if (t < NQ) {
        // layer-0 Rot matrix -> Rmat (8 floats/qubit)
        {
            float phi = qw[t * 3 + 0], th = qw[t * 3 + 1], om = qw[t * 3 + 2];
            float st_, ct;  sincosf(0.5f * th, &st_, &ct);
            float spo, cpo; sincosf(0.5f * (phi + om), &spo, &cpo);
            float spm, cpm; sincosf(0.5f * (phi - om), &spm, &cpm);
            Rmat[t * 8 + 0] =  cpo * ct;  Rmat[t * 8 + 1] = -spo * ct;
            Rmat[t * 8 + 2] = -cpm * st_; Rmat[t * 8 + 3] = -spm * st_;
            Rmat[t * 8 + 4] =  cpm * st_; Rmat[t * 8 + 5] = -spm * st_;
            Rmat[t * 8 + 6] =  cpo * ct;  Rmat[t * 8 + 7] =  spo * ct;
        }
        // layer-1 Rot: A = G† Z G Bloch coefficients
        {
            float phi = qw[30 + t * 3 + 0], th = qw[30 + t * 3 + 1], om = qw[30 + t * 3 + 2];
            float st_, ct;  sincosf(0.5f * th, &st_, &ct);
            float spo, cpo; sincosf(0.5f * (phi + om), &spo, &cpo);
            float spm, cpm; sincosf(0.5f * (phi - om), &spm, &cpm);
            float2 G00 = make_float2(cpo * ct, -spo * ct);
            float2 G01 = make_float2(-cpm * st_, -spm * st_);
            float2 G10 = make_float2(cpm * st_, -spm * st_);
            float2 G11 = make_float2(cpo * ct, spo * ct);
            float re = G00.x * G01.x + G00.y * G01.y - (G10.x * G11.x + G10.y * G11.y);
            float im = G00.x * G01.y - G00.y * G01.x - (G10.x * G11.y - G10.y * G11.x);
            float A00 = G00.x * G00.x + G00.y * G00.y - (G10.x * G10.x + G10.y * G10.y);
            float A11 = G01.x * G01.x + G01.y * G01.y - (G11.x * G11.x + G11.y * G11.y);
            abc[t][0] = re;
            abc[t][1] = -im;
            abc[t][2] = 0.5f * (A00 - A11);
        }
    }
    __syncthreads();
    write_term(t, abc, terms);
    write_term(t + 1024, abc, terms);
}

// ---------------------------------------------------------------------------
// Main kernel: 4 rows per block, 256 threads, 1024 blocks.
// ---------------------------------------------------------------------------
__global__ __launch_bounds__(256) void qse_main(
    const float* __restrict__ x,     // (4096,512)
    const float* __restrict__ W_in,  // (512,10)
    const float* __restrict__ b_in,  // (10)
    const float* __restrict__ W1,    // (10,64)
    const float* __restrict__ b1,    // (64)
    const float* __restrict__ W2,    // (64,256)
    const float* __restrict__ b2,    // (256)
    const uint2* __restrict__ terms, // (2048 padded)
    const float* __restrict__ Rmat,  // (10,8)
    float* __restrict__ out)         // (4096,256)
{
    __shared__ float ang[RPB][NQ];
    __shared__ float E2d[RPB][5][32];    // pair products, duplicated x2
    __shared__ float zsh[RPB][NQ];
    __shared__ float hsh[RPB][64];

    const int t = threadIdx.x;
    const int lane = t & 63;
    const int wv = t >> 6;               // wave id = row within block
    const int row0 = blockIdx.x * RPB;

    // ---- p1: wave wv computes angles for row row0+wv ----
    {
        float acc[NQ];
        #pragma unroll
        for (int q = 0; q < NQ; ++q) acc[q] = 0.f;
        const float* xr = x + (size_t)(row0 + wv) * 512;
        for (int k = 0; k < 8; ++k) {
            int j = lane + 64 * k;
            float xv = xr[j];
            const float2* wr = (const float2*)(W_in + j * NQ);
            #pragma unroll
            for (int h = 0; h < 5; ++h) {
                float2 w2 = wr[h];
                acc[2 * h]     = fmaf(xv, w2.x, acc[2 * h]);
                acc[2 * h + 1] = fmaf(xv, w2.y, acc[2 * h + 1]);
            }
        }
        #pragma unroll
        for (int off = 32; off > 0; off >>= 1) {
            #pragma unroll
            for (int q = 0; q < NQ; ++q) acc[q] += __shfl_xor(acc[q], off);
        }
        if (lane == 0) {
            #pragma unroll
            for (int q = 0; q < NQ; ++q) ang[wv][q] = acc[q];
        }
    }
    __syncthreads();

    // ---- p2: 80 threads build E2 pair-products directly (redundant sincos) ----
    if (t < 80) {
        const int rr = t / 20, rem = t % 20, p = rem >> 2, c1 = rem & 3;
        const int i0 = 2 * p, i1 = i0 + 1;
        float a0 = ang[rr][i0] + b_in[i0];
        float a1 = ang[rr][i1] + b_in[i1];
        float s0, c0f, s1, c1f;
        sincosf(0.5f * a0, &s0, &c0f);
        sincosf(0.5f * a1, &s1, &c1f);
        const float* Rp0 = Rmat + i0 * 8;
        const float* Rp1 = Rmat + i1 * 8;
        float2 u0 = make_float2(fmaf(Rp0[0], c0f, s0 * Rp0[3]), fmaf(Rp0[1], c0f, -s0 * Rp0[2]));
        float2 u1 = make_float2(fmaf(Rp0[4], c0f, s0 * Rp0[7]), fmaf(Rp0[5], c0f, -s0 * Rp0[6]));
        float ex0 = 2.f * (u0.x * u1.x + u0.y * u1.y);
        float ey0 = 2.f * (u0.x * u1.y - u0.y * u1.x);
        float ez0 = u0.x * u0.x + u0.y * u0.y - u1.x * u1.x - u1.y * u1.y;
        float2 v0 = make_float2(fmaf(Rp1[0], c1f, s1 * Rp1[3]), fmaf(Rp1[1], c1f, -s1 * Rp1[2]));
        float2 v1 = make_float2(fmaf(Rp1[4], c1f, s1 * Rp1[7]), fmaf(Rp1[5], c1f, -s1 * Rp1[6]));
        float ex1 = 2.f * (v0.x * v1.x + v0.y * v1.y);
        float ey1 = 2.f * (v0.x * v1.y - v0.y * v1.x);
        float ez1 = v0.x * v0.x + v0.y * v0.y - v1.x * v1.x - v1.y * v1.y;
        float e1 = (c1 == 0) ? 1.f : (c1 == 1) ? ex1 : (c1 == 2) ? ez1 : ey1;
        float e0arr[4] = {1.f, ex0, ez0, ey0};
        #pragma unroll
        for (int cc = 0; cc < 4; ++cc) {
            float v = e0arr[cc] * e1;
            int idx = cc | (c1 << 2);
            E2d[rr][p][2 * idx]     = v;
            E2d[rr][p][2 * idx + 1] = v;
        }
    }
    __syncthreads();

    // ---- p3: contract terms, branch-free uniform 8 slots/lane ----
    float accR[RPB] = {0.f, 0.f, 0.f, 0.f};
    {
        const float* E2p = &E2d[0][0][0] + (t & 1);
        #pragma unroll
        for (int s = 0; s < 8; ++s) {
            uint2 tms = terms[s * 256 + t];
            const float cf = __uint_as_float(tms.y);
            const unsigned nib = tms.x;
            #pragma unroll
            for (int rr = 0; rr < RPB; ++rr) {
                float pr = cf;
                #pragma unroll
                for (int p = 0; p < 5; ++p)
                    pr *= E2p[(rr * 5 + p) * 32 + 2 * ((nib >> (4 * p)) & 15u)];
                accR[rr] += pr;
            }
        }
    }
    // segment reduce: 8-wide everywhere, +2 steps for the 32-wide groups
    #pragma unroll
    for (int rr = 0; rr < RPB; ++rr) {
        accR[rr] += __shfl_xor(accR[rr], 1);
        accR[rr] += __shfl_xor(accR[rr], 2);
        accR[rr] += __shfl_xor(accR[rr], 4);
    }
    if (t < 192) {
        #pragma unroll
        for (int rr = 0; rr < RPB; ++rr) {
            accR[rr] += __shfl_xor(accR[rr], 8);
            accR[rr] += __shfl_xor(accR[rr], 16);
        }
    }
    {
        int qx = -1;
        if      (t == 0)   qx = 8;
        else if (t == 32)  qx = 9;
        else if (t == 64)  qx = 0;
        else if (t == 96)  qx = 1;
        else if (t == 128) qx = 6;
        else if (t == 160) qx = 7;
        else if (t == 192) qx = 4;
        else if (t == 200) qx = 5;
        else if (t == 208) qx = 2;
        else if (t == 216) qx = 3;
        if (qx >= 0) {
            #pragma unroll
            for (int rr = 0; rr < RPB; ++rr) zsh[rr][qx] = accR[rr];
        }
    }
    __syncthreads();

    // ---- p4: h = relu(z @ W1 + b1); 4 rows x 64 cols = 256 threads ----
    {
        const int rr = t >> 6, c = t & 63;
        float a = b1[c];
        #pragma unroll
        for (int i = 0; i < NQ; ++i) a = fmaf(zsh[rr][i], W1[i * 64 + c], a);
        hsh[rr][c] = fmaxf(a, 0.f);
    }
    __syncthreads();

    // ---- p5: out = tanh(h @ W2 + b2), thread owns column t for 4 rows ----
    {
        float oacc[RPB];
        #pragma unroll
        for (int rr = 0; rr < RPB; ++rr) oacc[rr] = b2[t];
        for (int j4 = 0; j4 < 16; ++j4) {
            float4 hv[RPB];
            #pragma unroll
            for (int rr = 0; rr < RPB; ++rr) hv[rr] = *(const float4*)&hsh[rr][4 * j4];
            const float w0 = W2[(4 * j4 + 0) * 256 + t];
            const float w1 = W2[(4 * j4 + 1) * 256 + t];
            const float w2 = W2[(4 * j4 + 2) * 256 + t];
            const float w3 = W2[(4 * j4 + 3) * 256 + t];
            #pragma unroll
            for (int rr = 0; rr < RPB; ++rr) {
                oacc[rr] = fmaf(hv[rr].x, w0, oacc[rr]);
                oacc[rr] = fmaf(hv[rr].y, w1, oacc[rr]);
                oacc[rr] = fmaf(hv[rr].z, w2, oacc[rr]);
                oacc[rr] = fmaf(hv[rr].w, w3, oacc[rr]);
            }
        }
        #pragma unroll
        for (int rr = 0; rr < RPB; ++rr)
            out[(size_t)(row0 + rr) * 256 + t] = tanhf(oacc[rr]);
    }
}

extern "C" void kernel_launch(void* const* d_in, const int* in_sizes, int n_in,
                              void* d_out, int out_size, void* d_ws, size_t ws_size,
                              hipStream_t stream) {
    const float* x    = (const float*)d_in[0];
    const float* W_in = (const float*)d_in[1];
    const float* b_in = (const float*)d_in[2];
    const float* qw   = (const float*)d_in[3];
    const float* W1   = (const float*)d_in[4];
    const float* b1   = (const float*)d_in[5];
    const float* W2   = (const float*)d_in[6];
    const float* b2   = (const float*)d_in[7];
    float* out = (float*)d_out;

    uint2* terms = (uint2*)d_ws;                        // 2048*8 = 16384 B
    float* Rmat  = (float*)((char*)d_ws + 16384);       // 80 floats

    qse_setup<<<1, 1024, 0, stream>>>(qw, terms, Rmat);
    // Diagnostic double-launch (idempotent): dur_us = floor + setup + 2*main.
    qse_main<<<4096 / RPB, 256, 0, stream>>>(x, W_in, b_in, W1, b1, W2, b2,
                                             (const uint2*)terms, (const float*)Rmat, out);
    qse_main<<<4096 / RPB, 256, 0, stream>>>(x, W_in, b_in, W1, b1, W2, b2,
                                             (const uint2*)terms, (const float*)Rmat, out);
}

// Round 7
// 102.545 us; speedup vs baseline: 1.2899x; 1.2899x over previous
//
#include <hip/hip_runtime.h>
#include <math.h>

#define NQ 10
// d_ws layout:
//   terms: 2048 * uint2  @ 0        (16384 B)
//   Rmat : 80 * float    @ 16384
//   ang  : 4096*10 float @ 32768    (163840 B)
//   z    : 4096*10 float @ 196608   (163840 B)

// Term table: 2048 slots, slot u: lane = u%256, s = u/256 (8 slots per lane).
// Lane groups (pow2-aligned for shfl_xor segment reduce):
//   0-31:q8  32-63:q9  64-95:q0  96-127:q1  128-159:q6  160-191:q7
//   192-199:q4  200-207:q5  208-215:q2  216-223:q3  224-255: coef 0
__device__ __forceinline__ void write_term(int u, const float abc[NQ][3],
                                           uint2* __restrict__ terms) {
    const int lane = u & 255, s = u >> 8;
    int q = -1, g0 = 0;
    if      (lane < 32)  { q = 8; g0 = 0;   }
    else if (lane < 64)  { q = 9; g0 = 32;  }
    else if (lane < 96)  { q = 0; g0 = 64;  }
    else if (lane < 128) { q = 1; g0 = 96;  }
    else if (lane < 160) { q = 6; g0 = 128; }
    else if (lane < 192) { q = 7; g0 = 160; }
    else if (lane < 200) { q = 4; g0 = 192; }
    else if (lane < 208) { q = 5; g0 = 200; }
    else if (lane < 216) { q = 2; g0 = 208; }
    else if (lane < 224) { q = 3; g0 = 216; }
    if (q < 0) { terms[u] = make_uint2(0u, 0u); return; }
    const int tau = (lane - g0) * 8 + s;

    int m = 1 << q;                       // ring-2 Z-string (pure toggles)
    for (int ii = NQ - 1; ii >= 0; --ii) {
        int tt = (ii + 2) % NQ;
        if ((m >> tt) & 1) m ^= 1 << ii;
    }
    const int Lp = __popc(m);
    int cnt = 1;
    for (int k = 0; k < Lp; ++k) cnt *= 3;
    if (tau >= cnt) { terms[u] = make_uint2(0u, 0u); return; }

    int rem = tau;                        // digits: 0->X, 1->Y, 2->Z
    unsigned xm = 0, zm = 0;
    float coef = 1.f;
    for (int i = 0; i < NQ; ++i) {
        if ((m >> i) & 1) {
            int d = rem % 3; rem /= 3;
            coef *= abc[i][d];
            if (d == 0)      { xm |= 1u << i; }
            else if (d == 1) { xm |= 1u << i; zm |= 1u << i; }
            else             { zm |= 1u << i; }
        }
    }
    unsigned sgn = 0;                     // ring-1 conj (i=9 first)
    for (int i = NQ - 1; i >= 0; --i) {
        int c = i, tt = (i + 1) % NQ;
        unsigned xc = (xm >> c) & 1u, zt = (zm >> tt) & 1u;
        unsigned xt = (xm >> tt) & 1u, zc = (zm >> c) & 1u;
        sgn ^= xc & zt & (xt ^ zc ^ 1u);
        xm ^= xc << tt;
        zm ^= zt << c;
    }
    if (sgn) coef = -coef;

    unsigned nib = 0;
    for (int p = 0; p < 5; ++p) {
        unsigned c0 = ((xm >> (2 * p)) & 1u) | (((zm >> (2 * p)) & 1u) << 1);
        unsigned c1 = ((xm >> (2 * p + 1)) & 1u) | (((zm >> (2 * p + 1)) & 1u) << 1);
        nib |= (c0 | (c1 << 2)) << (4 * p);
    }
    terms[u] = make_uint2(nib, __float_as_uint(coef));
}

__global__ __launch_bounds__(1024) void qse_setup(const float* __restrict__ qw,
                                                  uint2* __restrict__ terms,
                                                  float* __restrict__ Rmat) {
    __shared__ float abc[NQ][3];
    const int t = threadIdx.x;
    if (t < NQ) {
        {   // layer-0 Rot matrix -> Rmat
            float phi = qw[t * 3 + 0], th = qw[t * 3 + 1], om = qw[t * 3 + 2];
            float st_, ct;  sincosf(0.5f * th, &st_, &ct);
            float spo, cpo; sincosf(0.5f * (phi + om), &spo, &cpo);
            float spm, cpm; sincosf(0.5f * (phi - om), &spm, &cpm);
            Rmat[t * 8 + 0] =  cpo * ct;  Rmat[t * 8 + 1] = -spo * ct;
            Rmat[t * 8 + 2] = -cpm * st_; Rmat[t * 8 + 3] = -spm * st_;
            Rmat[t * 8 + 4] =  cpm * st_; Rmat[t * 8 + 5] = -spm * st_;
            Rmat[t * 8 + 6] =  cpo * ct;  Rmat[t * 8 + 7] =  spo * ct;
        }
        {   // layer-1 Rot: A = G† Z G Bloch coefficients
            float phi = qw[30 + t * 3 + 0], th = qw[30 + t * 3 + 1], om = qw[30 + t * 3 + 2];
            float st_, ct;  sincosf(0.5f * th, &st_, &ct);
            float spo, cpo; sincosf(0.5f * (phi + om), &spo, &cpo);
            float spm, cpm; sincosf(0.5f * (phi - om), &spm, &cpm);
            float2 G00 = make_float2(cpo * ct, -spo * ct);
            float2 G01 = make_float2(-cpm * st_, -spm * st_);
            float2 G10 = make_float2(cpm * st_, -spm * st_);
            float2 G11 = make_float2(cpo * ct, spo * ct);
            float re = G00.x * G01.x + G00.y * G01.y - (G10.x * G11.x + G10.y * G11.y);
            float im = G00.x * G01.y - G00.y * G01.x - (G10.x * G11.y - G10.y * G11.x);
            float A00 = G00.x * G00.x + G00.y * G00.y - (G10.x * G10.x + G10.y * G10.y);
            float A11 = G01.x * G01.x + G01.y * G01.y - (G11.x * G11.x + G11.y * G11.y);
            abc[t][0] = re;
            abc[t][1] = -im;
            abc[t][2] = 0.5f * (A00 - A11);
        }
    }
    __syncthreads();
    write_term(t, abc, terms);
    write_term(t + 1024, abc, terms);
}

// ---------------------------------------------------------------------------
// K1: ang[row][q] = x[row] @ W_in[:,q] + b_in[q].  Wave-per-row, 1024 blocks.
// ---------------------------------------------------------------------------
__global__ __launch_bounds__(256) void k_angles(const float* __restrict__ x,
                                                const float* __restrict__ W_in,
                                                const float* __restrict__ b_in,
                                                float* __restrict__ ang) {
    const int t = threadIdx.x, lane = t & 63, wv = t >> 6;
    const int row = blockIdx.x * 4 + wv;
    const float* xr = x + (size_t)row * 512;
    float acc[NQ];
    #pragma unroll
    for (int q = 0; q < NQ; ++q) acc[q] = 0.f;
    for (int k = 0; k < 8; ++k) {
        int j = lane + 64 * k;
        float xv = xr[j];
        const float2* wr = (const float2*)(W_in + j * NQ);
        #pragma unroll
        for (int h = 0; h < 5; ++h) {
            float2 w2 = wr[h];
            acc[2 * h]     = fmaf(xv, w2.x, acc[2 * h]);
            acc[2 * h + 1] = fmaf(xv, w2.y, acc[2 * h + 1]);
        }
    }
    #pragma unroll
    for (int off = 32; off > 0; off >>= 1) {
        #pragma unroll
        for (int q = 0; q < NQ; ++q) acc[q] += __shfl_xor(acc[q], off);
    }
    if (lane == 0) {
        #pragma unroll
        for (int q = 0; q < NQ; ++q) ang[row * NQ + q] = acc[q] + b_in[q];
    }
}

// ---------------------------------------------------------------------------
// K2: z[row][q] from ang via E2 pair-products + 882-term contraction.
// 4 rows/block, 256 threads, 1024 blocks, ONE barrier.
// ---------------------------------------------------------------------------
__global__ __launch_bounds__(256) void k_quantum(const float* __restrict__ ang,
                                                 const float* __restrict__ Rmat,
                                                 const uint2* __restrict__ terms,
                                                 float* __restrict__ z) {
    __shared__ float E2d[4][5][32];      // pair products, duplicated x2
    const int t = threadIdx.x;
    const int row0 = blockIdx.x * 4;

    if (t < 80) {                        // E2 build (redundant sincos)
        const int rr = t / 20, rem = t % 20, p = rem >> 2, c1 = rem & 3;
        const int i0 = 2 * p, i1 = i0 + 1;
        float a0 = ang[(row0 + rr) * NQ + i0];
        float a1 = ang[(row0 + rr) * NQ + i1];
        float s0, c0f, s1, c1f;
        sincosf(0.5f * a0, &s0, &c0f);
        sincosf(0.5f * a1, &s1, &c1f);
        const float* Rp0 = Rmat + i0 * 8;
        const float* Rp1 = Rmat + i1 * 8;
        float2 u0 = make_float2(fmaf(Rp0[0], c0f, s0 * Rp0[3]), fmaf(Rp0[1], c0f, -s0 * Rp0[2]));
        float2 u1 = make_float2(fmaf(Rp0[4], c0f, s0 * Rp0[7]), fmaf(Rp0[5], c0f, -s0 * Rp0[6]));
        float ex0 = 2.f * (u0.x * u1.x + u0.y * u1.y);
        float ey0 = 2.f * (u0.x * u1.y - u0.y * u1.x);
        float ez0 = u0.x * u0.x + u0.y * u0.y - u1.x * u1.x - u1.y * u1.y;
        float2 v0 = make_float2(fmaf(Rp1[0], c1f, s1 * Rp1[3]), fmaf(Rp1[1], c1f, -s1 * Rp1[2]));
        float2 v1 = make_float2(fmaf(Rp1[4], c1f, s1 * Rp1[7]), fmaf(Rp1[5], c1f, -s1 * Rp1[6]));
        float ex1 = 2.f * (v0.x * v1.x + v0.y * v1.y);
        float ey1 = 2.f * (v0.x * v1.y - v0.y * v1.x);
        float ez1 = v0.x * v0.x + v0.y * v0.y - v1.x * v1.x - v1.y * v1.y;
        float e1 = (c1 == 0) ? 1.f : (c1 == 1) ? ex1 : (c1 == 2) ? ez1 : ey1;
        float e0arr[4] = {1.f, ex0, ez0, ey0};
        #pragma unroll
        for (int cc = 0; cc < 4; ++cc) {
            float v = e0arr[cc] * e1;
            int idx = cc | (c1 << 2);
            E2d[rr][p][2 * idx]     = v;
            E2d[rr][p][2 * idx + 1] = v;
        }
    }
    __syncthreads();

    float accR[4] = {0.f, 0.f, 0.f, 0.f};
    {
        const float* E2p = &E2d[0][0][0] + (t & 1);
        #pragma unroll
        for (int s = 0; s < 8; ++s) {
            uint2 tms = terms[s * 256 + t];
            const float cf = __uint_as_float(tms.y);
            const unsigned nib = tms.x;
            #pragma unroll
            for (int rr = 0; rr < 4; ++rr) {
                float pr = cf;
                #pragma unroll
                for (int p = 0; p < 5; ++p)
                    pr *= E2p[(rr * 5 + p) * 32 + 2 * ((nib >> (4 * p)) & 15u)];
                accR[rr] += pr;
            }
        }
    }
    #pragma unroll
    for (int rr = 0; rr < 4; ++rr) {
        accR[rr] += __shfl_xor(accR[rr], 1);
        accR[rr] += __shfl_xor(accR[rr], 2);
        accR[rr] += __shfl_xor(accR[rr], 4);
    }
    if (t < 192) {
        #pragma unroll
        for (int rr = 0; rr < 4; ++rr) {
            accR[rr] += __shfl_xor(accR[rr], 8);
            accR[rr] += __shfl_xor(accR[rr], 16);
        }
    }
    int qx = -1;
    if      (t == 0)   qx = 8;
    else if (t == 32)  qx = 9;
    else if (t == 64)  qx = 0;
    else if (t == 96)  qx = 1;
    else if (t == 128) qx = 6;
    else if (t == 160) qx = 7;
    else if (t == 192) qx = 4;
    else if (t == 200) qx = 5;
    else if (t == 208) qx = 2;
    else if (t == 216) qx = 3;
    if (qx >= 0) {
        #pragma unroll
        for (int rr = 0; rr < 4; ++rr) z[(row0 + rr) * NQ + qx] = accR[rr];
    }
}

// ---------------------------------------------------------------------------
// K3: out = tanh(relu(z@W1+b1)@W2+b2).  8 rows/block, 256 threads, 512 blocks.
// ---------------------------------------------------------------------------
__global__ __launch_bounds__(256) void k_mlp(const float* __restrict__ z,
                                             const float* __restrict__ W1,
                                             const float* __restrict__ b1,
                                             const float* __restrict__ W2,
                                             const float* __restrict__ b2,
                                             float* __restrict__ out) {
    __shared__ float zsh[8][NQ];
    __shared__ float hsh[8][64];
    const int t = threadIdx.x;
    const int row0 = blockIdx.x * 8;

    if (t < 80) zsh[t / NQ][t % NQ] = z[(row0 + t / NQ) * NQ + t % NQ];
    __syncthreads();

    #pragma unroll
    for (int rep = 0; rep < 2; ++rep) {
        const int job = t + rep * 256;
        const int rr = job >> 6, c = job & 63;
        float a = b1[c];
        #pragma unroll
        for (int i = 0; i < NQ; ++i) a = fmaf(zsh[rr][i], W1[i * 64 + c], a);
        hsh[rr][c] = fmaxf(a, 0.f);
    }
    __syncthreads();

    float oacc[8];
    {
        const float bb = b2[t];
        #pragma unroll
        for (int rr = 0; rr < 8; ++rr) oacc[rr] = bb;
    }
    for (int j4 = 0; j4 < 16; ++j4) {
        const float w0 = W2[(4 * j4 + 0) * 256 + t];
        const float w1 = W2[(4 * j4 + 1) * 256 + t];
        const float w2 = W2[(4 * j4 + 2) * 256 + t];
        const float w3 = W2[(4 * j4 + 3) * 256 + t];
        #pragma unroll
        for (int rr = 0; rr < 8; ++rr) {
            float4 hv = *(const float4*)&hsh[rr][4 * j4];
            oacc[rr] = fmaf(hv.x, w0, oacc[rr]);
            oacc[rr] = fmaf(hv.y, w1, oacc[rr]);
            oacc[rr] = fmaf(hv.z, w2, oacc[rr]);
            oacc[rr] = fmaf(hv.w, w3, oacc[rr]);
        }
    }
    #pragma unroll
    for (int rr = 0; rr < 8; ++rr)
        out[(size_t)(row0 + rr) * 256 + t] = tanhf(oacc[rr]);
}

extern "C" void kernel_launch(void* const* d_in, const int* in_sizes, int n_in,
                              void* d_out, int out_size, void* d_ws, size_t ws_size,
                              hipStream_t stream) {
    const float* x    = (const float*)d_in[0];
    const float* W_in = (const float*)d_in[1];
    const float* b_in = (const float*)d_in[2];
    const float* qw   = (const float*)d_in[3];
    const float* W1   = (const float*)d_in[4];
    const float* b1   = (const float*)d_in[5];
    const float* W2   = (const float*)d_in[6];
    const float* b2   = (const float*)d_in[7];
    float* out = (float*)d_out;

    uint2* terms = (uint2*)d_ws;
    float* Rmat  = (float*)((char*)d_ws + 16384);
    float* ang   = (float*)((char*)d_ws + 32768);
    float* zbuf  = (float*)((char*)d_ws + 196608);

    qse_setup<<<1, 1024, 0, stream>>>(qw, terms, Rmat);
    k_angles <<<1024, 256, 0, stream>>>(x, W_in, b_in, ang);
    k_quantum<<<1024, 256, 0, stream>>>((const float*)ang, (const float*)Rmat,
                                        (const uint2*)terms, zbuf);
    k_mlp    <<<512, 256, 0, stream>>>((const float*)zbuf, W1, b1, W2, b2, out);
}

// Round 9
// 87.522 us; speedup vs baseline: 1.5113x; 1.1717x over previous
//
#include <hip/hip_runtime.h>
#include <math.h>

#define NQ 10
// d_ws layout: terms 2048*uint2 @ 0 (16384 B), Rmat 80*float @ 16384.

// Term table: 2048 slots, slot u: lane = u%256, s = u/256 (8 slots per lane).
// Lane groups (pow2-aligned for shfl_xor segment reduce):
//   0-31:q8  32-63:q9  64-95:q0  96-127:q1  128-159:q6  160-191:q7
//   192-199:q4  200-207:q5  208-215:q2  216-223:q3  224-255: coef 0
__device__ __forceinline__ void write_term(int u, const float abc[NQ][3],
                                           uint2* __restrict__ terms) {
    const int lane = u & 255, s = u >> 8;
    int q = -1, g0 = 0;
    if      (lane < 32)  { q = 8; g0 = 0;   }
    else if (lane < 64)  { q = 9; g0 = 32;  }
    else if (lane < 96)  { q = 0; g0 = 64;  }
    else if (lane < 128) { q = 1; g0 = 96;  }
    else if (lane < 160) { q = 6; g0 = 128; }
    else if (lane < 192) { q = 7; g0 = 160; }
    else if (lane < 200) { q = 4; g0 = 192; }
    else if (lane < 208) { q = 5; g0 = 200; }
    else if (lane < 216) { q = 2; g0 = 208; }
    else if (lane < 224) { q = 3; g0 = 216; }
    if (q < 0) { terms[u] = make_uint2(0u, 0u); return; }
    const int tau = (lane - g0) * 8 + s;

    int m = 1 << q;                       // ring-2 Z-string (pure toggles)
    for (int ii = NQ - 1; ii >= 0; --ii) {
        int tt = (ii + 2) % NQ;
        if ((m >> tt) & 1) m ^= 1 << ii;
    }
    const int Lp = __popc(m);
    int cnt = 1;
    for (int k = 0; k < Lp; ++k) cnt *= 3;
    if (tau >= cnt) { terms[u] = make_uint2(0u, 0u); return; }

    int rem = tau;                        // digits: 0->X, 1->Y, 2->Z
    unsigned xm = 0, zm = 0;
    float coef = 1.f;
    for (int i = 0; i < NQ; ++i) {
        if ((m >> i) & 1) {
            int d = rem % 3; rem /= 3;
            coef *= abc[i][d];
            if (d == 0)      { xm |= 1u << i; }
            else if (d == 1) { xm |= 1u << i; zm |= 1u << i; }
            else             { zm |= 1u << i; }
        }
    }
    unsigned sgn = 0;                     // ring-1 conj (i=9 first)
    for (int i = NQ - 1; i >= 0; --i) {
        int c = i, tt = (i + 1) % NQ;
        unsigned xc = (xm >> c) & 1u, zt = (zm >> tt) & 1u;
        unsigned xt = (xm >> tt) & 1u, zc = (zm >> c) & 1u;
        sgn ^= xc & zt & (xt ^ zc ^ 1u);
        xm ^= xc << tt;
        zm ^= zt << c;
    }
    if (sgn) coef = -coef;

    unsigned nib = 0;
    for (int p = 0; p < 5; ++p) {
        unsigned c0 = ((xm >> (2 * p)) & 1u) | (((zm >> (2 * p)) & 1u) << 1);
        unsigned c1 = ((xm >> (2 * p + 1)) & 1u) | (((zm >> (2 * p + 1)) & 1u) << 1);
        nib |= (c0 | (c1 << 2)) << (4 * p);
    }
    terms[u] = make_uint2(nib, __float_as_uint(coef));
}

// 8 blocks x 256 threads: block b writes slots b*256..b*256+255 (s = b).
__global__ __launch_bounds__(256) void qse_setup(const float* __restrict__ qw,
                                                 uint2* __restrict__ terms,
                                                 float* __restrict__ Rmat) {
    __shared__ float abc[NQ][3];
    const int t = threadIdx.x;
    const int b = blockIdx.x;
    if (t < NQ) {
        if (b == 0) {   // layer-0 Rot matrix -> Rmat
            float phi = qw[t * 3 + 0], th = qw[t * 3 + 1], om = qw[t * 3 + 2];
            float st_, ct;  sincosf(0.5f * th, &st_, &ct);
            float spo, cpo; sincosf(0.5f * (phi + om), &spo, &cpo);
            float spm, cpm; sincosf(0.5f * (phi - om), &spm, &cpm);
            Rmat[t * 8 + 0] =  cpo * ct;  Rmat[t * 8 + 1] = -spo * ct;
            Rmat[t * 8 + 2] = -cpm * st_; Rmat[t * 8 + 3] = -spm * st_;
            Rmat[t * 8 + 4] =  cpm * st_; Rmat[t * 8 + 5] = -spm * st_;
            Rmat[t * 8 + 6] =  cpo * ct;  Rmat[t * 8 + 7] =  spo * ct;
        }
        {   // layer-1 Rot: A = G† Z G Bloch coefficients
            float phi = qw[30 + t * 3 + 0], th = qw[30 + t * 3 + 1], om = qw[30 + t * 3 + 2];
            float st_, ct;  sincosf(0.5f * th, &st_, &ct);
            float spo, cpo; sincosf(0.5f * (phi + om), &spo, &cpo);
            float spm, cpm; sincosf(0.5f * (phi - om), &spm, &cpm);
            float2 G00 = make_float2(cpo * ct, -spo * ct);
            float2 G01 = make_float2(-cpm * st_, -spm * st_);
            float2 G10 = make_float2(cpm * st_, -spm * st_);
            float2 G11 = make_float2(cpo * ct, spo * ct);
            float re = G00.x * G01.x + G00.y * G01.y - (G10.x * G11.x + G10.y * G11.y);
            float im = G00.x * G01.y - G00.y * G01.x - (G10.x * G11.y - G10.y * G11.x);
            float A00 = G00.x * G00.x + G00.y * G00.y - (G10.x * G10.x + G10.y * G10.y);
            float A11 = G01.x * G01.x + G01.y * G01.y - (G11.x * G11.x + G11.y * G11.y);
            abc[t][0] = re;
            abc[t][1] = -im;
            abc[t][2] = 0.5f * (A00 - A11);
        }
    }
    __syncthreads();
    write_term(b * 256 + t, abc, terms);
}

__device__ __forceinline__ float fast_tanh(float v) {
    float e = __expf(2.f * v);
    return 1.f - 2.f / (e + 1.f);     // saturates correctly at +/-inf
}

// ---------------------------------------------------------------------------
// Mega kernel: angles -> E2 -> term contraction -> MLP. 4 rows/block,
// 256 threads, 1024 blocks, 4 barriers. Terms prefetched to registers
// before the x-stream so their L2 latency hides under the HBM read.
// ---------------------------------------------------------------------------
__global__ __launch_bounds__(256) void qse_mega(
    const float* __restrict__ x,     // (4096,512)
    const float* __restrict__ W_in,  // (512,10)
    const float* __restrict__ b_in,  // (10)
    const float* __restrict__ W1,    // (10,64)
    const float* __restrict__ b1,    // (64)
    const float* __restrict__ W2,    // (64,256)
    const float* __restrict__ b2,    // (256)
    const uint2* __restrict__ terms, // (2048)
    const float* __restrict__ Rmat,  // (10,8)
    float* __restrict__ out)         // (4096,256)
{
    __shared__ float angsh[4][NQ];
    __shared__ float E2d[4][5][32];      // pair products, duplicated x2
    __shared__ float zsh[4][NQ];
    __shared__ float hsh[4][64];

    const int t = threadIdx.x;
    const int lane = t & 63;
    const int wv = t >> 6;
    const int row0 = blockIdx.x * 4;

    // ---- prefetch term slots to registers (used in phase C) ----
    uint2 tm[8];
    #pragma unroll
    for (int s = 0; s < 8; ++s) tm[s] = terms[s * 256 + t];

    // ---- phase A: wave wv computes angles for row row0+wv (float4 x) ----
    {
        float acc[NQ];
        #pragma unroll
        for (int q = 0; q < NQ; ++q) acc[q] = 0.f;
        const float4* xr4 = (const float4*)(x + (size_t)(row0 + wv) * 512);
        #pragma unroll
        for (int k = 0; k < 2; ++k) {
            const int j4 = lane + 64 * k;
            const float4 xv = xr4[j4];
            const float* wr = W_in + (4 * j4) * NQ;
            #pragma unroll
            for (int h = 0; h < 5; ++h) {
                float2 w2 = ((const float2*)wr)[h];
                acc[2*h]   = fmaf(xv.x, w2.x, acc[2*h]);
                acc[2*h+1] = fmaf(xv.x, w2.y, acc[2*h+1]);
            }
            #pragma unroll
            for (int h = 0; h < 5; ++h) {
                float2 w2 = ((const float2*)(wr + NQ))[h];
                acc[2*h]   = fmaf(xv.y, w2.x, acc[2*h]);
                acc[2*h+1] = fmaf(xv.y, w2.y, acc[2*h+1]);
            }
            #pragma unroll
            for (int h = 0; h < 5; ++h) {
                float2 w2 = ((const float2*)(wr + 2 * NQ))[h];
                acc[2*h]   = fmaf(xv.z, w2.x, acc[2*h]);
                acc[2*h+1] = fmaf(xv.z, w2.y, acc[2*h+1]);
            }
            #pragma unroll
            for (int h = 0; h < 5; ++h) {
                float2 w2 = ((const float2*)(wr + 3 * NQ))[h];
                acc[2*h]   = fmaf(xv.w, w2.x, acc[2*h]);
                acc[2*h+1] = fmaf(xv.w, w2.y, acc[2*h+1]);
            }
        }
        #pragma unroll
        for (int off = 32; off > 0; off >>= 1) {
            #pragma unroll
            for (int q = 0; q < NQ; ++q) acc[q] += __shfl_xor(acc[q], off);
        }
        if (lane == 0) {
            #pragma unroll
            for (int q = 0; q < NQ; ++q) angsh[wv][q] = acc[q] + b_in[q];
        }
    }
    __syncthreads();

    // ---- phase B: threads 0..79 build E2 pair-products (redundant sincos) ----
    if (t < 80) {
        const int rr = t / 20, rem = t % 20, p = rem >> 2, c1 = rem & 3;
        const int i0 = 2 * p, i1 = i0 + 1;
        float a0 = angsh[rr][i0];
        float a1 = angsh[rr][i1];
        float s0, c0f, s1, c1f;
        sincosf(0.5f * a0, &s0, &c0f);
        sincosf(0.5f * a1, &s1, &c1f);
        const float* Rp0 = Rmat + i0 * 8;
        const float* Rp1 = Rmat + i1 * 8;
        float2 u0 = make_float2(fmaf(Rp0[0], c0f, s0 * Rp0[3]), fmaf(Rp0[1], c0f, -s0 * Rp0[2]));
        float2 u1 = make_float2(fmaf(Rp0[4], c0f, s0 * Rp0[7]), fmaf(Rp0[5], c0f, -s0 * Rp0[6]));
        float ex0 = 2.f * (u0.x * u1.x + u0.y * u1.y);
        float ey0 = 2.f * (u0.x * u1.y - u0.y * u1.x);
        float ez0 = u0.x * u0.x + u0.y * u0.y - u1.x * u1.x - u1.y * u1.y;
        float2 v0 = make_float2(fmaf(Rp1[0], c1f, s1 * Rp1[3]), fmaf(Rp1[1], c1f, -s1 * Rp1[2]));
        float2 v1 = make_float2(fmaf(Rp1[4], c1f, s1 * Rp1[7]), fmaf(Rp1[5], c1f, -s1 * Rp1[6]));
        float ex1 = 2.f * (v0.x * v1.x + v0.y * v1.y);
        float ey1 = 2.f * (v0.x * v1.y - v0.y * v1.x);
        float ez1 = v0.x * v0.x + v0.y * v0.y - v1.x * v1.x - v1.y * v1.y;
        float e1 = (c1 == 0) ? 1.f : (c1 == 1) ? ex1 : (c1 == 2) ? ez1 : ey1;
        float e0arr[4] = {1.f, ex0, ez0, ey0};
        #pragma unroll
        for (int cc = 0; cc < 4; ++cc) {
            float v = e0arr[cc] * e1;
            int idx = cc | (c1 << 2);
            E2d[rr][p][2 * idx]     = v;
            E2d[rr][p][2 * idx + 1] = v;
        }
    }
    __syncthreads();

    // ---- phase C: contract terms (registers) against E2d ----
    float accR[4] = {0.f, 0.f, 0.f, 0.f};
    {
        const float* E2p = &E2d[0][0][0] + (t & 1);
        #pragma unroll
        for (int s = 0; s < 8; ++s) {
            const float cf = __uint_as_float(tm[s].y);
            const unsigned nib = tm[s].x;
            #pragma unroll
            for (int rr = 0; rr < 4; ++rr) {
                float pr = cf;
                #pragma unroll
                for (int p = 0; p < 5; ++p)
                    pr *= E2p[(rr * 5 + p) * 32 + 2 * ((nib >> (4 * p)) & 15u)];
                accR[rr] += pr;
            }
        }
    }
    #pragma unroll
    for (int rr = 0; rr < 4; ++rr) {
        accR[rr] += __shfl_xor(accR[rr], 1);
        accR[rr] += __shfl_xor(accR[rr], 2);
        accR[rr] += __shfl_xor(accR[rr], 4);
    }
    if (t < 192) {
        #pragma unroll
        for (int rr = 0; rr < 4; ++rr) {
            accR[rr] += __shfl_xor(accR[rr], 8);
            accR[rr] += __shfl_xor(accR[rr], 16);
        }
    }
    {
        int qx = -1;
        if      (t == 0)   qx = 8;
        else if (t == 32)  qx = 9;
        else if (t == 64)  qx = 0;
        else if (t == 96)  qx = 1;
        else if (t == 128) qx = 6;
        else if (t == 160) qx = 7;
        else if (t == 192) qx = 4;
        else if (t == 200) qx = 5;
        else if (t == 208) qx = 2;
        else if (t == 216) qx = 3;
        if (qx >= 0) {
            #pragma unroll
            for (int rr = 0; rr < 4; ++rr) zsh[rr][qx] = accR[rr];
        }
    }
    __syncthreads();

    // ---- phase D: h = relu(z @ W1 + b1); 4 rows x 64 cols ----
    {
        const int rr = t >> 6, c = t & 63;
        float a = b1[c];
        #pragma unroll
        for (int i = 0; i < NQ; ++i) a = fmaf(zsh[rr][i], W1[i * 64 + c], a);
        hsh[rr][c] = fmaxf(a, 0.f);
    }
    __syncthreads();

    // ---- phase E: out = tanh(h @ W2 + b2), thread owns column t, 4 rows ----
    {
        float oacc[4];
        const float bb = b2[t];
        #pragma unroll
        for (int rr = 0; rr < 4; ++rr) oacc[rr] = bb;
        for (int j4 = 0; j4 < 16; ++j4) {
            const float w0 = W2[(4 * j4 + 0) * 256 + t];
            const float w1 = W2[(4 * j4 + 1) * 256 + t];
            const float w2 = W2[(4 * j4 + 2) * 256 + t];
            const float w3 = W2[(4 * j4 + 3) * 256 + t];
            #pragma unroll
            for (int rr = 0; rr < 4; ++rr) {
                float4 hv = *(const float4*)&hsh[rr][4 * j4];
                oacc[rr] = fmaf(hv.x, w0, oacc[rr]);
                oacc[rr] = fmaf(hv.y, w1, oacc[rr]);
                oacc[rr] = fmaf(hv.z, w2, oacc[rr]);
                oacc[rr] = fmaf(hv.w, w3, oacc[rr]);
            }
        }
        #pragma unroll
        for (int rr = 0; rr < 4; ++rr)
            out[(size_t)(row0 + rr) * 256 + t] = fast_tanh(oacc[rr]);
    }
}

extern "C" void kernel_launch(void* const* d_in, const int* in_sizes, int n_in,
                              void* d_out, int out_size, void* d_ws, size_t ws_size,
                              hipStream_t stream) {
    const float* x    = (const float*)d_in[0];
    const float* W_in = (const float*)d_in[1];
    const float* b_in = (const float*)d_in[2];
    const float* qw   = (const float*)d_in[3];
    const float* W1   = (const float*)d_in[4];
    const float* b1   = (const float*)d_in[5];
    const float* W2   = (const float*)d_in[6];
    const float* b2   = (const float*)d_in[7];
    float* out = (float*)d_out;

    uint2* terms = (uint2*)d_ws;
    float* Rmat  = (float*)((char*)d_ws + 16384);

    qse_setup<<<8, 256, 0, stream>>>(qw, terms, Rmat);
    qse_mega<<<1024, 256, 0, stream>>>(x, W_in, b_in, W1, b1, W2, b2,
                                       (const uint2*)terms, (const float*)Rmat, out);
}

// Round 10
// 84.923 us; speedup vs baseline: 1.5575x; 1.0306x over previous
//
#include <hip/hip_runtime.h>
#include <math.h>

#define NQ 10
// d_ws layout: terms 2048*uint2 @ 0 (16384 B), Rmat 80*float @ 16384.

// Term table: slot u = s*256 + lane. Variable slots per wave:
//   wave0 (lanes 0-63):   8 slots   wave1 (64-127): 3 slots
//   wave2 (128-191):      3 slots   wave3 (192-255): 4 slots
// Lane groups (pow2-aligned for shfl_xor segment reduce):
//   0-31:q8  32-63:q9  64-95:q0  96-127:q1  128-159:q6  160-191:q7
//   192-199:q4  200-207:q5  208-215:q2  216-223:q3  224-255: coef 0
// Valid term counts: q8/q9=243, q0/q1/q6/q7=81, q4/q5=27, q2/q3=9 (total 882).
// Packed word: bits 0-15 = site codes 0-7 (2b each), bits 16-19 = sites 8-9.
__device__ __forceinline__ void write_term(int u, const float abc[NQ][3],
                                           uint2* __restrict__ terms) {
    const int lane = u & 255, s = u >> 8;
    const int wvv = lane >> 6;
    const int nsl = (wvv == 0) ? 8 : ((wvv == 3) ? 4 : 3);
    int q = -1, g0 = 0;
    if      (lane < 32)  { q = 8; g0 = 0;   }
    else if (lane < 64)  { q = 9; g0 = 32;  }
    else if (lane < 96)  { q = 0; g0 = 64;  }
    else if (lane < 128) { q = 1; g0 = 96;  }
    else if (lane < 160) { q = 6; g0 = 128; }
    else if (lane < 192) { q = 7; g0 = 160; }
    else if (lane < 200) { q = 4; g0 = 192; }
    else if (lane < 208) { q = 5; g0 = 200; }
    else if (lane < 216) { q = 2; g0 = 208; }
    else if (lane < 224) { q = 3; g0 = 216; }
    if (q < 0 || s >= nsl) { terms[u] = make_uint2(0u, 0u); return; }
    const int tau = (lane - g0) * nsl + s;

    int m = 1 << q;                       // ring-2 Z-string (pure toggles)
    for (int ii = NQ - 1; ii >= 0; --ii) {
        int tt = (ii + 2) % NQ;
        if ((m >> tt) & 1) m ^= 1 << ii;
    }
    const int Lp = __popc(m);
    int cnt = 1;
    for (int k = 0; k < Lp; ++k) cnt *= 3;
    if (tau >= cnt) { terms[u] = make_uint2(0u, 0u); return; }

    int rem = tau;                        // digits: 0->X, 1->Y, 2->Z
    unsigned xm = 0, zm = 0;
    float coef = 1.f;
    for (int i = 0; i < NQ; ++i) {
        if ((m >> i) & 1) {
            int d = rem % 3; rem /= 3;
            coef *= abc[i][d];
            if (d == 0)      { xm |= 1u << i; }
            else if (d == 1) { xm |= 1u << i; zm |= 1u << i; }
            else             { zm |= 1u << i; }
        }
    }
    unsigned sgn = 0;                     // ring-1 conj (i=9 first)
    for (int i = NQ - 1; i >= 0; --i) {
        int c = i, tt = (i + 1) % NQ;
        unsigned xc = (xm >> c) & 1u, zt = (zm >> tt) & 1u;
        unsigned xt = (xm >> tt) & 1u, zc = (zm >> c) & 1u;
        sgn ^= xc & zt & (xt ^ zc ^ 1u);
        xm ^= xc << tt;
        zm ^= zt << c;
    }
    if (sgn) coef = -coef;

    unsigned w = 0;                       // pack per-site 2-bit codes (x | z<<1)
    for (int i = 0; i < NQ; ++i) {
        unsigned code = ((xm >> i) & 1u) | (((zm >> i) & 1u) << 1);
        w |= code << (2 * i);
    }
    terms[u] = make_uint2(w, __float_as_uint(coef));
}

// 8 blocks x 256 threads: block b writes slots b*256..b*256+255 (s = b).
__global__ __launch_bounds__(256) void qse_setup(const float* __restrict__ qw,
                                                 uint2* __restrict__ terms,
                                                 float* __restrict__ Rmat) {
    __shared__ float abc[NQ][3];
    const int t = threadIdx.x;
    const int b = blockIdx.x;
    if (t < NQ) {
        if (b == 0) {   // layer-0 Rot matrix -> Rmat
            float phi = qw[t * 3 + 0], th = qw[t * 3 + 1], om = qw[t * 3 + 2];
            float st_, ct;  sincosf(0.5f * th, &st_, &ct);
            float spo, cpo; sincosf(0.5f * (phi + om), &spo, &cpo);
            float spm, cpm; sincosf(0.5f * (phi - om), &spm, &cpm);
            Rmat[t * 8 + 0] =  cpo * ct;  Rmat[t * 8 + 1] = -spo * ct;
            Rmat[t * 8 + 2] = -cpm * st_; Rmat[t * 8 + 3] = -spm * st_;
            Rmat[t * 8 + 4] =  cpm * st_; Rmat[t * 8 + 5] = -spm * st_;
            Rmat[t * 8 + 6] =  cpo * ct;  Rmat[t * 8 + 7] =  spo * ct;
        }
        {   // layer-1 Rot: A = G† Z G Bloch coefficients
            float phi = qw[30 + t * 3 + 0], th = qw[30 + t * 3 + 1], om = qw[30 + t * 3 + 2];
            float st_, ct;  sincosf(0.5f * th, &st_, &ct);
            float spo, cpo; sincosf(0.5f * (phi + om), &spo, &cpo);
            float spm, cpm; sincosf(0.5f * (phi - om), &spm, &cpm);
            float2 G00 = make_float2(cpo * ct, -spo * ct);
            float2 G01 = make_float2(-cpm * st_, -spm * st_);
            float2 G10 = make_float2(cpm * st_, -spm * st_);
            float2 G11 = make_float2(cpo * ct, spo * ct);
            float re = G00.x * G01.x + G00.y * G01.y - (G10.x * G11.x + G10.y * G11.y);
            float im = G00.x * G01.y - G00.y * G01.x - (G10.x * G11.y - G10.y * G11.x);
            float A00 = G00.x * G00.x + G00.y * G00.y - (G10.x * G10.x + G10.y * G10.y);
            float A11 = G01.x * G01.x + G01.y * G01.y - (G11.x * G11.x + G11.y * G11.y);
            abc[t][0] = re;
            abc[t][1] = -im;
            abc[t][2] = 0.5f * (A00 - A11);
        }
    }
    __syncthreads();
    write_term(b * 256 + t, abc, terms);
}

__device__ __forceinline__ float fast_tanh(float v) {
    float e = __expf(2.f * v);
    return 1.f - 2.f / (e + 1.f);     // saturates correctly at +/-inf
}

// ---------------------------------------------------------------------------
// Mega kernel: angles -> E2 -> E4 quad tables -> term contraction -> MLP.
// 4 rows/block, 256 threads, 1024 blocks, 5 barriers.
// ---------------------------------------------------------------------------
__global__ __launch_bounds__(256) void qse_mega(
    const float* __restrict__ x,     // (4096,512)
    const float* __restrict__ W_in,  // (512,10)
    const float* __restrict__ b_in,  // (10)
    const float* __restrict__ W1,    // (10,64)
    const float* __restrict__ b1,    // (64)
    const float* __restrict__ W2,    // (64,256)
    const float* __restrict__ b2,    // (256)
    const uint2* __restrict__ terms, // (2048)
    const float* __restrict__ Rmat,  // (10,8)
    float* __restrict__ out)         // (4096,256)
{
    __shared__ float angsh[4][NQ];
    __shared__ float E2tmp[4][5][16];    // per-pair products (no dup)
    __shared__ float E4d[4][2][256];     // quad products (sites 0-3, 4-7)
    __shared__ float E2P[4][32];         // pair 4 (sites 8-9), duplicated x2
    __shared__ float zsh[4][NQ];
    __shared__ float hsh[4][64];

    const int t = threadIdx.x;
    const int lane = t & 63;
    const int wv = t >> 6;
    const int row0 = blockIdx.x * 4;
    const int nsl = (wv == 0) ? 8 : ((wv == 3) ? 4 : 3);

    // ---- prefetch term slots to registers (used in phase C) ----
    uint2 tm[8];
    #pragma unroll
    for (int s = 0; s < 8; ++s)
        tm[s] = (s < nsl) ? terms[s * 256 + t] : make_uint2(0u, 0u);

    // ---- phase A: wave wv computes angles for row row0+wv (float4 x) ----
    {
        float acc[NQ];
        #pragma unroll
        for (int q = 0; q < NQ; ++q) acc[q] = 0.f;
        const float4* xr4 = (const float4*)(x + (size_t)(row0 + wv) * 512);
        #pragma unroll
        for (int k = 0; k < 2; ++k) {
            const int j4 = lane + 64 * k;
            const float4 xv = xr4[j4];
            const float* wr = W_in + (4 * j4) * NQ;
            #pragma unroll
            for (int h = 0; h < 5; ++h) {
                float2 w2 = ((const float2*)wr)[h];
                acc[2*h]   = fmaf(xv.x, w2.x, acc[2*h]);
                acc[2*h+1] = fmaf(xv.x, w2.y, acc[2*h+1]);
            }
            #pragma unroll
            for (int h = 0; h < 5; ++h) {
                float2 w2 = ((const float2*)(wr + NQ))[h];
                acc[2*h]   = fmaf(xv.y, w2.x, acc[2*h]);
                acc[2*h+1] = fmaf(xv.y, w2.y, acc[2*h+1]);
            }
            #pragma unroll
            for (int h = 0; h < 5; ++h) {
                float2 w2 = ((const float2*)(wr + 2 * NQ))[h];
                acc[2*h]   = fmaf(xv.z, w2.x, acc[2*h]);
                acc[2*h+1] = fmaf(xv.z, w2.y, acc[2*h+1]);
            }
            #pragma unroll
            for (int h = 0; h < 5; ++h) {
                float2 w2 = ((const float2*)(wr + 3 * NQ))[h];
                acc[2*h]   = fmaf(xv.w, w2.x, acc[2*h]);
                acc[2*h+1] = fmaf(xv.w, w2.y, acc[2*h+1]);
            }
        }
        #pragma unroll
        for (int off = 32; off > 0; off >>= 1) {
            #pragma unroll
            for (int q = 0; q < NQ; ++q) acc[q] += __shfl_xor(acc[q], off);
        }
        if (lane == 0) {
            #pragma unroll
            for (int q = 0; q < NQ; ++q) angsh[wv][q] = acc[q] + b_in[q];
        }
    }
    __syncthreads();

    // ---- phase B1: threads 0..79 build E2 pair tables (redundant sincos) ----
    if (t < 80) {
        const int rr = t / 20, rem = t % 20, p = rem >> 2, c1 = rem & 3;
        const int i0 = 2 * p, i1 = i0 + 1;
        float a0 = angsh[rr][i0];
        float a1 = angsh[rr][i1];
        float s0, c0f, s1, c1f;
        sincosf(0.5f * a0, &s0, &c0f);
        sincosf(0.5f * a1, &s1, &c1f);
        const float* Rp0 = Rmat + i0 * 8;
        const float* Rp1 = Rmat + i1 * 8;
        float2 u0 = make_float2(fmaf(Rp0[0], c0f, s0 * Rp0[3]), fmaf(Rp0[1], c0f, -s0 * Rp0[2]));
        float2 u1 = make_float2(fmaf(Rp0[4], c0f, s0 * Rp0[7]), fmaf(Rp0[5], c0f, -s0 * Rp0[6]));
        float ex0 = 2.f * (u0.x * u1.x + u0.y * u1.y);
        float ey0 = 2.f * (u0.x * u1.y - u0.y * u1.x);
        float ez0 = u0.x * u0.x + u0.y * u0.y - u1.x * u1.x - u1.y * u1.y;
        float2 v0 = make_float2(fmaf(Rp1[0], c1f, s1 * Rp1[3]), fmaf(Rp1[1], c1f, -s1 * Rp1[2]));
        float2 v1 = make_float2(fmaf(Rp1[4], c1f, s1 * Rp1[7]), fmaf(Rp1[5], c1f, -s1 * Rp1[6]));
        float ex1 = 2.f * (v0.x * v1.x + v0.y * v1.y);
        float ey1 = 2.f * (v0.x * v1.y - v0.y * v1.x);
        float ez1 = v0.x * v0.x + v0.y * v0.y - v1.x * v1.x - v1.y * v1.y;
        float e1 = (c1 == 0) ? 1.f : (c1 == 1) ? ex1 : (c1 == 2) ? ez1 : ey1;
        float e0arr[4] = {1.f, ex0, ez0, ey0};
        #pragma unroll
        for (int cc = 0; cc < 4; ++cc) {
            float v = e0arr[cc] * e1;
            int idx = cc | (c1 << 2);
            E2tmp[rr][p][idx] = v;
            if (p == 4) {                 // sites 8-9: duplicated pair table
                E2P[rr][2 * idx]     = v;
                E2P[rr][2 * idx + 1] = v;
            }
        }
    }
    __syncthreads();

    // ---- phase B2: build E4 quad tables (2048 entries, 8 per thread) ----
    #pragma unroll
    for (int k = 0; k < 8; ++k) {
        const int rr = k >> 1, qd = k & 1;
        E4d[rr][qd][t] = E2tmp[rr][2 * qd][t & 15] * E2tmp[rr][2 * qd + 1][t >> 4];
    }
    __syncthreads();

    // ---- phase C: contract terms (registers) against E4/E2P ----
    float accR[4] = {0.f, 0.f, 0.f, 0.f};
    {
        const int par = t & 1;
        #pragma unroll
        for (int s = 0; s < 8; ++s) {
            if (s < nsl) {
                const float cf = __uint_as_float(tm[s].y);
                const unsigned w = tm[s].x;
                const int i0 = w & 255, i1 = (w >> 8) & 255, ip = (w >> 16) & 15;
                #pragma unroll
                for (int rr = 0; rr < 4; ++rr) {
                    float pr = cf * E4d[rr][0][i0];
                    pr *= E4d[rr][1][i1];
                    pr *= E2P[rr][2 * ip + par];
                    accR[rr] += pr;
                }
            }
        }
    }
    #pragma unroll
    for (int rr = 0; rr < 4; ++rr) {
        accR[rr] += __shfl_xor(accR[rr], 1);
        accR[rr] += __shfl_xor(accR[rr], 2);
        accR[rr] += __shfl_xor(accR[rr], 4);
    }
    if (t < 192) {
        #pragma unroll
        for (int rr = 0; rr < 4; ++rr) {
            accR[rr] += __shfl_xor(accR[rr], 8);
            accR[rr] += __shfl_xor(accR[rr], 16);
        }
    }
    {
        int qx = -1;
        if      (t == 0)   qx = 8;
        else if (t == 32)  qx = 9;
        else if (t == 64)  qx = 0;
        else if (t == 96)  qx = 1;
        else if (t == 128) qx = 6;
        else if (t == 160) qx = 7;
        else if (t == 192) qx = 4;
        else if (t == 200) qx = 5;
        else if (t == 208) qx = 2;
        else if (t == 216) qx = 3;
        if (qx >= 0) {
            #pragma unroll
            for (int rr = 0; rr < 4; ++rr) zsh[rr][qx] = accR[rr];
        }
    }
    __syncthreads();

    // ---- phase D: h = relu(z @ W1 + b1); 4 rows x 64 cols ----
    {
        const int rr = t >> 6, c = t & 63;
        float a = b1[c];
        #pragma unroll
        for (int i = 0; i < NQ; ++i) a = fmaf(zsh[rr][i], W1[i * 64 + c], a);
        hsh[rr][c] = fmaxf(a, 0.f);
    }
    __syncthreads();

    // ---- phase E: out = tanh(h @ W2 + b2), thread owns column t, 4 rows ----
    {
        float oacc[4];
        const float bb = b2[t];
        #pragma unroll
        for (int rr = 0; rr < 4; ++rr) oacc[rr] = bb;
        for (int j4 = 0; j4 < 16; ++j4) {
            const float w0 = W2[(4 * j4 + 0) * 256 + t];
            const float w1 = W2[(4 * j4 + 1) * 256 + t];
            const float w2 = W2[(4 * j4 + 2) * 256 + t];
            const float w3 = W2[(4 * j4 + 3) * 256 + t];
            #pragma unroll
            for (int rr = 0; rr < 4; ++rr) {
                float4 hv = *(const float4*)&hsh[rr][4 * j4];
                oacc[rr] = fmaf(hv.x, w0, oacc[rr]);
                oacc[rr] = fmaf(hv.y, w1, oacc[rr]);
                oacc[rr] = fmaf(hv.z, w2, oacc[rr]);
                oacc[rr] = fmaf(hv.w, w3, oacc[rr]);
            }
        }
        #pragma unroll
        for (int rr = 0; rr < 4; ++rr)
            out[(size_t)(row0 + rr) * 256 + t] = fast_tanh(oacc[rr]);
    }
}

extern "C" void kernel_launch(void* const* d_in, const int* in_sizes, int n_in,
                              void* d_out, int out_size, void* d_ws, size_t ws_size,
                              hipStream_t stream) {
    const float* x    = (const float*)d_in[0];
    const float* W_in = (const float*)d_in[1];
    const float* b_in = (const float*)d_in[2];
    const float* qw   = (const float*)d_in[3];
    const float* W1   = (const float*)d_in[4];
    const float* b1   = (const float*)d_in[5];
    const float* W2   = (const float*)d_in[6];
    const float* b2   = (const float*)d_in[7];
    float* out = (float*)d_out;

    uint2* terms = (uint2*)d_ws;
    float* Rmat  = (float*)((char*)d_ws + 16384);

    qse_setup<<<8, 256, 0, stream>>>(qw, terms, Rmat);
    qse_mega<<<1024, 256, 0, stream>>>(x, W_in, b_in, W1, b1, W2, b2,
                                       (const uint2*)terms, (const float*)Rmat, out);
}

// Round 11
// 83.130 us; speedup vs baseline: 1.5911x; 1.0216x over previous
//
#include <hip/hip_runtime.h>
#include <math.h>

#define NQ 10

// ---------------------------------------------------------------------------
// Compile-time term table. Slot u = s*256 + lane. Variable slots per wave:
//   wave0 (lanes 0-63): 8   wave1: 3   wave2: 3   wave3: 4
// Lane groups (pow2-aligned for shfl_xor segment reduce):
//   0-31:q8  32-63:q9  64-95:q0  96-127:q1  128-159:q6  160-191:q7
//   192-199:q4  200-207:q5  208-215:q2  216-223:q3  224-255: invalid
// Valid term counts: q8/q9=243, q0/q1/q6/q7=81, q4/q5=27, q2/q3=9 (total 882).
// post: packed POST-ring1-conj site codes (x|z<<1), 2b/site, sites 0-9 in bits 0-19.
// pre : packed PRE-conj codes (bits 0-19) | sign<<20 | valid<<21.
// Term value = sign * [prod_i a(i, pre_i)] * [prod_i E(i, post_i)], with the
// products factored as quad tables: idx0 = w&255 (sites0-3), idx1 = (w>>8)&255
// (sites4-7), idxp = (w>>16)&15 (sites8-9).
// ---------------------------------------------------------------------------
struct TP { unsigned post, pre; };
struct TermsTab { TP t[2048]; };

constexpr TermsTab build_terms() {
    TermsTab T{};
    for (int u = 0; u < 2048; ++u) {
        const int lane = u & 255, s = u >> 8;
        const int wvv = lane >> 6;
        const int nsl = (wvv == 0) ? 8 : ((wvv == 3) ? 4 : 3);
        int q = -1, g0 = 0;
        if      (lane < 32)  { q = 8; g0 = 0;   }
        else if (lane < 64)  { q = 9; g0 = 32;  }
        else if (lane < 96)  { q = 0; g0 = 64;  }
        else if (lane < 128) { q = 1; g0 = 96;  }
        else if (lane < 160) { q = 6; g0 = 128; }
        else if (lane < 192) { q = 7; g0 = 160; }
        else if (lane < 200) { q = 4; g0 = 192; }
        else if (lane < 208) { q = 5; g0 = 200; }
        else if (lane < 216) { q = 2; g0 = 208; }
        else if (lane < 224) { q = 3; g0 = 216; }
        T.t[u].post = 0u; T.t[u].pre = 0u;            // invalid default
        if (q < 0 || s >= nsl) continue;
        const int tau = (lane - g0) * nsl + s;

        int m = 1 << q;                               // ring-2 Z-string
        for (int ii = 9; ii >= 0; --ii) {
            int tt = (ii + 2) % 10;
            if ((m >> tt) & 1) m ^= 1 << ii;
        }
        int Lp = 0;
        for (int i = 0; i < 10; ++i) Lp += (m >> i) & 1;
        int cnt = 1;
        for (int k = 0; k < Lp; ++k) cnt *= 3;
        if (tau >= cnt) continue;

        int rem = tau;                                // digits: 0->X,1->Y,2->Z
        unsigned xm = 0, zm = 0;
        for (int i = 0; i < 10; ++i) {
            if ((m >> i) & 1) {
                int d = rem % 3; rem /= 3;
                if (d == 0)      { xm |= 1u << i; }
                else if (d == 1) { xm |= 1u << i; zm |= 1u << i; }
                else             { zm |= 1u << i; }
            }
        }
        unsigned wpre = 0;                            // pre-conj pack
        for (int i = 0; i < 10; ++i)
            wpre |= (((xm >> i) & 1u) | (((zm >> i) & 1u) << 1)) << (2 * i);

        unsigned sgn = 0;                             // ring-1 conj (i=9 first)
        for (int i = 9; i >= 0; --i) {
            int c = i, tt = (i + 1) % 10;
            unsigned xc = (xm >> c) & 1u, zt = (zm >> tt) & 1u;
            unsigned xt = (xm >> tt) & 1u, zc = (zm >> c) & 1u;
            sgn ^= xc & zt & (xt ^ zc ^ 1u);
            xm ^= xc << tt;
            zm ^= zt << c;
        }
        unsigned wpost = 0;                           // post-conj pack
        for (int i = 0; i < 10; ++i)
            wpost |= (((xm >> i) & 1u) | (((zm >> i) & 1u) << 1)) << (2 * i);

        T.t[u].post = wpost;
        T.t[u].pre  = wpre | (sgn << 20) | (1u << 21);
    }
    return T;
}

__device__ constexpr TermsTab TERMS = build_terms();

__device__ __forceinline__ float fast_tanh(float v) {
    float e = __expf(2.f * v);
    return 1.f - 2.f / (e + 1.f);     // saturates correctly at +/-inf
}

// ---------------------------------------------------------------------------
// Single mega kernel: W_in LDS-transpose + angles -> Rot/abc -> E2/A2 ->
// E4/A4 -> term contraction -> MLP. 4 rows/block, 256 threads, 1024 blocks.
// ---------------------------------------------------------------------------
__global__ __launch_bounds__(256) void qse_mega(
    const float* __restrict__ x,     // (4096,512)
    const float* __restrict__ W_in,  // (512,10)
    const float* __restrict__ b_in,  // (10)
    const float* __restrict__ qw,    // (2,10,3)
    const float* __restrict__ W1,    // (10,64)
    const float* __restrict__ b1,    // (64)
    const float* __restrict__ W2,    // (64,256)
    const float* __restrict__ b2,    // (256)
    float* __restrict__ out)         // (4096,256)
{
    __shared__ float Wt[NQ][512];        // transposed W_in (20 KB)
    __shared__ float Rsh[NQ][8];         // layer-0 Rot matrices
    __shared__ float absh[NQ][3];        // layer-1 A = G†ZG Bloch coefs
    __shared__ float angsh[4][NQ];
    __shared__ float E2tmp[4][5][16];    // per-pair Bloch products
    __shared__ float E4d[4][2][256];     // quad products (sites 0-3, 4-7)
    __shared__ float E2P[4][32];         // pair (sites 8-9), duplicated x2
    __shared__ float A2tmp[5][16];       // per-pair abc products
    __shared__ float A4d[2][256];        // abc quad tables
    __shared__ float A2P[32];            // abc pair (sites 8-9), dup x2
    __shared__ float zsh[4][NQ];
    __shared__ float hsh[4][64];

    const int t = threadIdx.x;
    const int lane = t & 63;
    const int wv = t >> 6;
    const int row0 = blockIdx.x * 4;
    const int nsl = (wv == 0) ? 8 : ((wv == 3) ? 4 : 3);

    // ---- issue x loads (8 coalesced dwords per thread, wave wv = row wv) ----
    const float* xr = x + (size_t)(row0 + wv) * 512;
    float xv[8];
    #pragma unroll
    for (int k = 0; k < 8; ++k) xv[k] = xr[lane + 64 * k];

    // ---- prefetch term codes (constexpr table in .rodata/L2) ----
    TP tp[8];
    #pragma unroll
    for (int s = 0; s < 8; ++s)
        tp[s] = (s < nsl) ? TERMS.t[s * 256 + t] : TP{0u, 0u};

    // ---- stage W_in transposed into LDS (coalesced float4 reads) ----
    #pragma unroll
    for (int i = 0; i < 5; ++i) {
        const int e4 = t + 256 * i;
        const float4 v = ((const float4*)W_in)[e4];
        const int e = 4 * e4;
        Wt[(e + 0) % NQ][(e + 0) / NQ] = v.x;
        Wt[(e + 1) % NQ][(e + 1) / NQ] = v.y;
        Wt[(e + 2) % NQ][(e + 2) / NQ] = v.z;
        Wt[(e + 3) % NQ][(e + 3) / NQ] = v.w;
    }

    // ---- threads 0-9: per-block Rot matrices + abc (hides under loads) ----
    if (t < NQ) {
        {   // layer-0 Rot
            float phi = qw[t * 3 + 0], th = qw[t * 3 + 1], om = qw[t * 3 + 2];
            float st_, ct;  sincosf(0.5f * th, &st_, &ct);
            float spo, cpo; sincosf(0.5f * (phi + om), &spo, &cpo);
            float spm, cpm; sincosf(0.5f * (phi - om), &spm, &cpm);
            Rsh[t][0] =  cpo * ct;  Rsh[t][1] = -spo * ct;
            Rsh[t][2] = -cpm * st_; Rsh[t][3] = -spm * st_;
            Rsh[t][4] =  cpm * st_; Rsh[t][5] = -spm * st_;
            Rsh[t][6] =  cpo * ct;  Rsh[t][7] =  spo * ct;
        }
        {   // layer-1: A = G† Z G Bloch coefficients
            float phi = qw[30 + t * 3 + 0], th = qw[30 + t * 3 + 1], om = qw[30 + t * 3 + 2];
            float st_, ct;  sincosf(0.5f * th, &st_, &ct);
            float spo, cpo; sincosf(0.5f * (phi + om), &spo, &cpo);
            float spm, cpm; sincosf(0.5f * (phi - om), &spm, &cpm);
            float2 G00 = make_float2(cpo * ct, -spo * ct);
            float2 G01 = make_float2(-cpm * st_, -spm * st_);
            float2 G10 = make_float2(cpm * st_, -spm * st_);
            float2 G11 = make_float2(cpo * ct, spo * ct);
            float re = G00.x * G01.x + G00.y * G01.y - (G10.x * G11.x + G10.y * G11.y);
            float im = G00.x * G01.y - G00.y * G01.x - (G10.x * G11.y - G10.y * G11.x);
            float A00 = G00.x * G00.x + G00.y * G00.y - (G10.x * G10.x + G10.y * G10.y);
            float A11 = G01.x * G01.x + G01.y * G01.y - (G11.x * G11.x + G11.y * G11.y);
            absh[t][0] = re;
            absh[t][1] = -im;
            absh[t][2] = 0.5f * (A00 - A11);
        }
    }
    __syncthreads();

    // ---- phase A: angles GEMM from LDS (conflict-free stride-1 reads) ----
    {
        float acc[NQ];
        #pragma unroll
        for (int q = 0; q < NQ; ++q) acc[q] = 0.f;
        #pragma unroll
        for (int k = 0; k < 8; ++k) {
            const int j = lane + 64 * k;
            const float xj = xv[k];
            #pragma unroll
            for (int q = 0; q < NQ; ++q) acc[q] = fmaf(xj, Wt[q][j], acc[q]);
        }
        #pragma unroll
        for (int off = 32; off > 0; off >>= 1) {
            #pragma unroll
            for (int q = 0; q < NQ; ++q) acc[q] += __shfl_xor(acc[q], off);
        }
        if (lane == 0) {
            #pragma unroll
            for (int q = 0; q < NQ; ++q) angsh[wv][q] = acc[q] + b_in[q];
        }
    }
    __syncthreads();

    // ---- phase B1: E2 pair tables (t<80) + A2 abc tables (t in 80..99) ----
    if (t < 80) {
        const int rr = t / 20, rem = t % 20, p = rem >> 2, c1 = rem & 3;
        const int i0 = 2 * p, i1 = i0 + 1;
        float a0 = angsh[rr][i0];
        float a1 = angsh[rr][i1];
        float s0, c0f, s1, c1f;
        sincosf(0.5f * a0, &s0, &c0f);
        sincosf(0.5f * a1, &s1, &c1f);
        const float* Rp0 = Rsh[i0];
        const float* Rp1 = Rsh[i1];
        float2 u0 = make_float2(fmaf(Rp0[0], c0f, s0 * Rp0[3]), fmaf(Rp0[1], c0f, -s0 * Rp0[2]));
        float2 u1 = make_float2(fmaf(Rp0[4], c0f, s0 * Rp0[7]), fmaf(Rp0[5], c0f, -s0 * Rp0[6]));
        float ex0 = 2.f * (u0.x * u1.x + u0.y * u1.y);
        float ey0 = 2.f * (u0.x * u1.y - u0.y * u1.x);
        float ez0 = u0.x * u0.x + u0.y * u0.y - u1.x * u1.x - u1.y * u1.y;
        float2 v0 = make_float2(fmaf(Rp1[0], c1f, s1 * Rp1[3]), fmaf(Rp1[1], c1f, -s1 * Rp1[2]));
        float2 v1 = make_float2(fmaf(Rp1[4], c1f, s1 * Rp1[7]), fmaf(Rp1[5], c1f, -s1 * Rp1[6]));
        float ex1 = 2.f * (v0.x * v1.x + v0.y * v1.y);
        float ey1 = 2.f * (v0.x * v1.y - v0.y * v1.x);
        float ez1 = v0.x * v0.x + v0.y * v0.y - v1.x * v1.x - v1.y * v1.y;
        float e1 = (c1 == 0) ? 1.f : (c1 == 1) ? ex1 : (c1 == 2) ? ez1 : ey1;
        float e0arr[4] = {1.f, ex0, ez0, ey0};
        #pragma unroll
        for (int cc = 0; cc < 4; ++cc) {
            float v = e0arr[cc] * e1;
            int idx = cc | (c1 << 2);
            E2tmp[rr][p][idx] = v;
            if (p == 4) {
                E2P[rr][2 * idx]     = v;
                E2P[rr][2 * idx + 1] = v;
            }
        }
    } else if (t < 100) {
        const int rem = t - 80, p = rem >> 2, c1 = rem & 3;
        const int i0 = 2 * p, i1 = i0 + 1;
        // a(i, code): code0 -> 1, code1 -> X=absh[i][0], code2 -> Z=absh[i][2], code3 -> Y=absh[i][1]
        float b1v = (c1 == 0) ? 1.f : (c1 == 1) ? absh[i1][0] : (c1 == 2) ? absh[i1][2] : absh[i1][1];
        float a0arr[4] = {1.f, absh[i0][0], absh[i0][2], absh[i0][1]};
        #pragma unroll
        for (int cc = 0; cc < 4; ++cc) {
            float v = a0arr[cc] * b1v;
            int idx = cc | (c1 << 2);
            A2tmp[p][idx] = v;
            if (p == 4) {
                A2P[2 * idx]     = v;
                A2P[2 * idx + 1] = v;
            }
        }
    }
    __syncthreads();

    // ---- phase B2: quad tables (E4: 8/thread, A4: 2/thread) ----
    #pragma unroll
    for (int k = 0; k < 8; ++k) {
        const int rr = k >> 1, qd = k & 1;
        E4d[rr][qd][t] = E2tmp[rr][2 * qd][t & 15] * E2tmp[rr][2 * qd + 1][t >> 4];
    }
    A4d[0][t] = A2tmp[0][t & 15] * A2tmp[1][t >> 4];
    A4d[1][t] = A2tmp[2][t & 15] * A2tmp[3][t >> 4];
    __syncthreads();

    // ---- phase C: contract terms against E4/E2P with A-table coefs ----
    float accR[4] = {0.f, 0.f, 0.f, 0.f};
    {
        const int par = t & 1;
        #pragma unroll
        for (int s = 0; s < 8; ++s) {
            if (s < nsl) {
                const unsigned pre = tp[s].pre, post = tp[s].post;
                float cf = A4d[0][pre & 255] * A4d[1][(pre >> 8) & 255]
                         * A2P[2 * ((pre >> 16) & 15) + par];
                cf = (pre & (1u << 21)) ? cf : 0.f;
                cf = (pre & (1u << 20)) ? -cf : cf;
                const int i0 = post & 255, i1 = (post >> 8) & 255, ip = (post >> 16) & 15;
                #pragma unroll
                for (int rr = 0; rr < 4; ++rr) {
                    float pr = cf * E4d[rr][0][i0];
                    pr *= E4d[rr][1][i1];
                    pr *= E2P[rr][2 * ip + par];
                    accR[rr] += pr;
                }
            }
        }
    }
    #pragma unroll
    for (int rr = 0; rr < 4; ++rr) {
        accR[rr] += __shfl_xor(accR[rr], 1);
        accR[rr] += __shfl_xor(accR[rr], 2);
        accR[rr] += __shfl_xor(accR[rr], 4);
    }
    if (t < 192) {
        #pragma unroll
        for (int rr = 0; rr < 4; ++rr) {
            accR[rr] += __shfl_xor(accR[rr], 8);
            accR[rr] += __shfl_xor(accR[rr], 16);
        }
    }
    {
        int qx = -1;
        if      (t == 0)   qx = 8;
        else if (t == 32)  qx = 9;
        else if (t == 64)  qx = 0;
        else if (t == 96)  qx = 1;
        else if (t == 128) qx = 6;
        else if (t == 160) qx = 7;
        else if (t == 192) qx = 4;
        else if (t == 200) qx = 5;
        else if (t == 208) qx = 2;
        else if (t == 216) qx = 3;
        if (qx >= 0) {
            #pragma unroll
            for (int rr = 0; rr < 4; ++rr) zsh[rr][qx] = accR[rr];
        }
    }
    __syncthreads();

    // ---- phase D: h = relu(z @ W1 + b1); 4 rows x 64 cols ----
    {
        const int rr = t >> 6, c = t & 63;
        float a = b1[c];
        #pragma unroll
        for (int i = 0; i < NQ; ++i) a = fmaf(zsh[rr][i], W1[i * 64 + c], a);
        hsh[rr][c] = fmaxf(a, 0.f);
    }
    __syncthreads();

    // ---- phase E: out = tanh(h @ W2 + b2), thread owns column t, 4 rows ----
    {
        float oacc[4];
        const float bb = b2[t];
        #pragma unroll
        for (int rr = 0; rr < 4; ++rr) oacc[rr] = bb;
        for (int j4 = 0; j4 < 16; ++j4) {
            const float w0 = W2[(4 * j4 + 0) * 256 + t];
            const float w1 = W2[(4 * j4 + 1) * 256 + t];
            const float w2 = W2[(4 * j4 + 2) * 256 + t];
            const float w3 = W2[(4 * j4 + 3) * 256 + t];
            #pragma unroll
            for (int rr = 0; rr < 4; ++rr) {
                float4 hv = *(const float4*)&hsh[rr][4 * j4];
                oacc[rr] = fmaf(hv.x, w0, oacc[rr]);
                oacc[rr] = fmaf(hv.y, w1, oacc[rr]);
                oacc[rr] = fmaf(hv.z, w2, oacc[rr]);
                oacc[rr] = fmaf(hv.w, w3, oacc[rr]);
            }
        }
        #pragma unroll
        for (int rr = 0; rr < 4; ++rr)
            out[(size_t)(row0 + rr) * 256 + t] = fast_tanh(oacc[rr]);
    }
}

extern "C" void kernel_launch(void* const* d_in, const int* in_sizes, int n_in,
                              void* d_out, int out_size, void* d_ws, size_t ws_size,
                              hipStream_t stream) {
    const float* x    = (const float*)d_in[0];
    const float* W_in = (const float*)d_in[1];
    const float* b_in = (const float*)d_in[2];
    const float* qw   = (const float*)d_in[3];
    const float* W1   = (const float*)d_in[4];
    const float* b1   = (const float*)d_in[5];
    const float* W2   = (const float*)d_in[6];
    const float* b2   = (const float*)d_in[7];
    float* out = (float*)d_out;

    qse_mega<<<1024, 256, 0, stream>>>(x, W_in, b_in, qw, W1, b1, W2, b2, out);
}